// Round 1
// baseline (44.588 us; speedup 1.0000x reference)
//
#include <hip/hip_runtime.h>
#include <math.h>

#define IN_DIM  512
#define OUT_DIM 512
#define BATCH   2
#define NPTS    50000
#define TOTAL   (BATCH * NPTS)

// Kernel 1: v[b][d] = sum_e mat[d][e] * s[b][e]   (v: [2][512], 4 KB in d_ws)
// Grid: BATCH*8 blocks x 256 threads. Block handles one b and a chunk of 64 d's.
// Each wave dots one mat row (2 KB, coalesced float4) against s[b] staged in LDS.
__global__ __launch_bounds__(256) void dgi_compute_v(
    const float* __restrict__ mat, const float* __restrict__ s,
    float* __restrict__ v)
{
    const int b     = blockIdx.x >> 3;
    const int chunk = blockIdx.x & 7;

    __shared__ float4 s_sh[OUT_DIM / 4];  // s[b] as 128 float4
    if (threadIdx.x < OUT_DIM / 4) {
        s_sh[threadIdx.x] =
            reinterpret_cast<const float4*>(s + (size_t)b * OUT_DIM)[threadIdx.x];
    }
    __syncthreads();

    const int wave = threadIdx.x >> 6;
    const int lane = threadIdx.x & 63;

    #pragma unroll 4
    for (int i = 0; i < 16; ++i) {
        const int d = chunk * 64 + i * 4 + wave;
        const float4* mrow =
            reinterpret_cast<const float4*>(mat + (size_t)d * OUT_DIM);
        const float4 m0 = mrow[lane];
        const float4 m1 = mrow[lane + 64];
        const float4 s0 = s_sh[lane];
        const float4 s1 = s_sh[lane + 64];
        float acc = m0.x * s0.x + m0.y * s0.y + m0.z * s0.z + m0.w * s0.w
                  + m1.x * s1.x + m1.y * s1.y + m1.z * s1.z + m1.w * s1.w;
        #pragma unroll
        for (int off = 32; off; off >>= 1) acc += __shfl_xor(acc, off);
        if (lane == 0) v[b * IN_DIM + d] = acc;
    }
}

// Kernel 2: out[row] = sigmoid( z[row,:] . v[b,:] ),  row in [0, 100000), b = row/NPTS.
// One wave per row: 64 lanes x 2 float4 = 512 floats, coalesced 16B/lane.
// Grid-stride over waves; v kept in registers, reloaded only when b changes.
__global__ __launch_bounds__(256) void dgi_score(
    const float* __restrict__ z, const float* __restrict__ v,
    float* __restrict__ out)
{
    const int lane   = threadIdx.x & 63;
    const int wave   = (blockIdx.x * blockDim.x + threadIdx.x) >> 6;
    const int nwaves = (gridDim.x * blockDim.x) >> 6;

    int   b_cur = -1;
    float4 v0, v1;

    for (int row = wave; row < TOTAL; row += nwaves) {
        const int b = (row >= NPTS) ? 1 : 0;
        if (b != b_cur) {
            b_cur = b;
            const float4* vr =
                reinterpret_cast<const float4*>(v + (size_t)b * IN_DIM);
            v0 = vr[lane];
            v1 = vr[lane + 64];
        }
        const float4* zr =
            reinterpret_cast<const float4*>(z + (size_t)row * IN_DIM);
        const float4 z0 = zr[lane];
        const float4 z1 = zr[lane + 64];

        float acc = z0.x * v0.x + z0.y * v0.y + z0.z * v0.z + z0.w * v0.w
                  + z1.x * v1.x + z1.y * v1.y + z1.z * v1.z + z1.w * v1.w;

        #pragma unroll
        for (int off = 32; off; off >>= 1) acc += __shfl_xor(acc, off);

        if (lane == 0) {
            out[row] = 1.0f / (1.0f + __expf(-acc));
        }
    }
}

extern "C" void kernel_launch(void* const* d_in, const int* in_sizes, int n_in,
                              void* d_out, int out_size, void* d_ws, size_t ws_size,
                              hipStream_t stream) {
    const float* z   = (const float*)d_in[0];   // [2, 50000, 512] f32
    const float* s   = (const float*)d_in[1];   // [2, 512] f32
    const float* mat = (const float*)d_in[2];   // [512, 512] f32
    float* out = (float*)d_out;                 // [2, 50000] f32
    float* v   = (float*)d_ws;                  // [2, 512] f32 scratch

    dgi_compute_v<<<BATCH * 8, 256, 0, stream>>>(mat, s, v);
    dgi_score<<<2048, 256, 0, stream>>>(z, v, out);
}

// Round 2
// 38.688 us; speedup vs baseline: 1.1525x; 1.1525x over previous
//
#include <hip/hip_runtime.h>
#include <math.h>

#define IN_DIM  512
#define OUT_DIM 512
#define BATCH   2
#define NPTS    50000
#define TOTAL   (BATCH * NPTS)
#define RPW     14                      // rows per wave in kernel 2

typedef float f4 __attribute__((ext_vector_type(4)));

__device__ __forceinline__ f4 ntload(const f4* p) {
    return __builtin_nontemporal_load(p);
}

__device__ __forceinline__ float dot8(f4 a0, f4 a1, f4 b0, f4 b1) {
    return a0[0]*b0[0] + a0[1]*b0[1] + a0[2]*b0[2] + a0[3]*b0[3]
         + a1[0]*b1[0] + a1[1]*b1[1] + a1[2]*b1[2] + a1[3]*b1[3];
}

__device__ __forceinline__ float wred(float x) {
    #pragma unroll
    for (int off = 32; off; off >>= 1) x += __shfl_xor(x, off);
    return x;
}

// Kernel 1: v[b][d] = sum_e mat[d][e] * s[b][e]   (v: [2][512] f32 in d_ws)
// 256 blocks x 256 threads = 1024 waves, one per (b,d). No LDS, no barrier;
// s is 4 KB -> L2-resident after first touch, mat rows read coalesced float4.
__global__ __launch_bounds__(256) void dgi_compute_v(
    const float* __restrict__ mat, const float* __restrict__ s,
    float* __restrict__ v)
{
    const int lane = threadIdx.x & 63;
    const int W    = (int)((blockIdx.x * blockDim.x + threadIdx.x) >> 6);
    const int b    = W >> 9;
    const int d    = W & 511;

    const f4* mrow = reinterpret_cast<const f4*>(mat + (size_t)d * OUT_DIM);
    const f4* srow = reinterpret_cast<const f4*>(s   + (size_t)b * OUT_DIM);
    const f4 m0 = mrow[lane], m1 = mrow[lane + 64];
    const f4 s0 = srow[lane], s1 = srow[lane + 64];

    float acc = wred(dot8(m0, m1, s0, s1));
    if (lane == 0) v[b * IN_DIM + d] = acc;
}

// Kernel 2: out[row] = sigmoid( z[row,:] . v[b,:] ), b = row >= NPTS.
// One wave per 14 contiguous rows (7143 full waves, all co-resident).
// Unroll x2: 4 float4 nontemporal loads in flight, two independent
// shuffle-reduce chains. v kept in registers, reloaded only at the
// (single) batch-boundary-straddling wave.
__global__ __launch_bounds__(256) void dgi_score(
    const float* __restrict__ z, const float* __restrict__ v,
    float* __restrict__ out)
{
    const int lane = threadIdx.x & 63;
    const int wave = (int)((blockIdx.x * blockDim.x + threadIdx.x) >> 6);
    const long base = (long)wave * RPW;
    if (base >= TOTAL) return;
    const int cnt = (TOTAL - base < RPW) ? (int)(TOTAL - base) : RPW;

    int b_cur = -1;
    f4 v0, v1;

    int i = 0;
    for (; i + 1 < cnt; i += 2) {
        const long rowA = base + i;
        const long rowB = rowA + 1;
        const f4* zA = reinterpret_cast<const f4*>(z + rowA * IN_DIM);
        const f4* zB = reinterpret_cast<const f4*>(z + rowB * IN_DIM);
        const f4 a0 = ntload(zA + lane), a1 = ntload(zA + lane + 64);
        const f4 c0 = ntload(zB + lane), c1 = ntload(zB + lane + 64);

        const int bA = (rowA >= NPTS);
        if (bA != b_cur) {
            b_cur = bA;
            const f4* vr = reinterpret_cast<const f4*>(v + (size_t)bA * IN_DIM);
            v0 = vr[lane]; v1 = vr[lane + 64];
        }
        float accA = dot8(a0, a1, v0, v1);

        const int bB = (rowB >= NPTS);
        if (bB != b_cur) {
            b_cur = bB;
            const f4* vr = reinterpret_cast<const f4*>(v + (size_t)bB * IN_DIM);
            v0 = vr[lane]; v1 = vr[lane + 64];
        }
        float accB = dot8(c0, c1, v0, v1);

        accA = wred(accA);
        accB = wred(accB);
        if (lane == 0) {
            out[rowA] = 1.0f / (1.0f + __expf(-accA));
            out[rowB] = 1.0f / (1.0f + __expf(-accB));
        }
    }
    if (i < cnt) {
        const long row = base + i;
        const f4* zr = reinterpret_cast<const f4*>(z + row * IN_DIM);
        const f4 a0 = ntload(zr + lane), a1 = ntload(zr + lane + 64);
        const int b = (row >= NPTS);
        if (b != b_cur) {
            const f4* vr = reinterpret_cast<const f4*>(v + (size_t)b * IN_DIM);
            v0 = vr[lane]; v1 = vr[lane + 64];
        }
        float acc = wred(dot8(a0, a1, v0, v1));
        if (lane == 0) out[row] = 1.0f / (1.0f + __expf(-acc));
    }
}

extern "C" void kernel_launch(void* const* d_in, const int* in_sizes, int n_in,
                              void* d_out, int out_size, void* d_ws, size_t ws_size,
                              hipStream_t stream) {
    const float* z   = (const float*)d_in[0];   // [2, 50000, 512] f32
    const float* s   = (const float*)d_in[1];   // [2, 512] f32
    const float* mat = (const float*)d_in[2];   // [512, 512] f32
    float* out = (float*)d_out;                 // [2, 50000] f32
    float* v   = (float*)d_ws;                  // [2, 512] f32 scratch

    dgi_compute_v<<<BATCH * 128, 256, 0, stream>>>(mat, s, v);

    const int nwaves = (TOTAL + RPW - 1) / RPW;         // 7143
    const int blocks = (nwaves + 3) / 4;                // 1786
    dgi_score<<<blocks, 256, 0, stream>>>(z, v, out);
}